// Round 16
// baseline (104.355 us; speedup 1.0000x reference)
//
#include <hip/hip_runtime.h>
#include <hip/hip_fp16.h>

// Problem constants: B=2, L=16, N=10000, FIN=8, H=64, P=12, E=80000, K=3
#define NN   10000
#define LL   16
#define FINC 8
#define HH   64
#define PP   12
#define EE   80000
#define BLH  256   // (b,lp,h) = 2*2*64 — only l=14,15 feed out[:,:,-1] (K=3, pad=1)
#define CAP  64    // per-row edge bucket capacity; E/N = 8, P(deg>64) ~ 0
#define RS   132   // fused-tile row stride (pad 128+4): 16B-aligned
#define EQ   (EE / 4)   // 20000 — edges per k2 batch

// ---------------------------------------------------------------------------
// k1 v3h: 2500 blocks x 256 threads, 4 nodes per block (fully unrolled).
// W_in in registers; x via wave-uniform scalar loads; OUTPUT IN FP16
// (halves the L3-BW-bound gather traffic).  Blocks 0..39 zero deg.
// ---------------------------------------------------------------------------
__global__ __launch_bounds__(256) void k1_input_proj(
        const float* __restrict__ x, const float* __restrict__ W_in,
        const float* __restrict__ b_in, __half* __restrict__ hsmall,
        int* __restrict__ deg) {
    const int t  = threadIdx.x;
    const int bl = __builtin_amdgcn_readfirstlane(t >> 6);  // wave-uniform (b*2+lp)
    const int h  = t & 63;
    const int b  = bl >> 1, lp = bl & 1;

    if (blockIdx.x < 40) {                 // zero deg (10000 ints over 40 blocks)
        int di = blockIdx.x * 256 + t;
        if (di < NN) deg[di] = 0;
    }

    float w[FINC];
#pragma unroll
    for (int f = 0; f < FINC; ++f) w[f] = W_in[f * HH + h];   // coalesced, L2-hot
    const float bias = b_in[h];
    const float* xb = x + (size_t)(b * LL + 14 + lp) * NN * FINC;
    const int g = blockIdx.x * 4;

#pragma unroll
    for (int nn = 0; nn < 4; ++nn) {
        const int n = g + nn;
        float4 xa = *(const float4*)&xb[(size_t)n * 8];       // uniform -> s_load
        float4 xc = *(const float4*)&xb[(size_t)n * 8 + 4];
        float acc = bias;
        acc = fmaf(xa.x, w[0], acc); acc = fmaf(xa.y, w[1], acc);
        acc = fmaf(xa.z, w[2], acc); acc = fmaf(xa.w, w[3], acc);
        acc = fmaf(xc.x, w[4], acc); acc = fmaf(xc.y, w[5], acc);
        acc = fmaf(xc.z, w[6], acc); acc = fmaf(xc.w, w[7], acc);
        hsmall[(size_t)n * BLH + t] = __float2half_rn(fmaxf(acc, 0.f));
    }
}

// ---------------------------------------------------------------------------
// k2 v2: bucketed CSR build with x4 MLP — each thread owns 4 edges (strided
// batches, coalesced within each batch); the 4 atomic round-trips and the 4
// scatter writes are independent chains in flight.  Tail threads pack W_tcn
// taps {0,1} into Wt[k][o] (k = lp*64+i).
// ---------------------------------------------------------------------------
__global__ __launch_bounds__(256) void k2_build(
        const int* __restrict__ row, const int* __restrict__ col,
        const float* __restrict__ vals, int* __restrict__ deg,
        int2* __restrict__ bucket, const float* __restrict__ W_tcn,
        float* __restrict__ Wt) {
    const int tid = blockIdx.x * 256 + threadIdx.x;
    if (tid < EQ) {
        int   r[4], c[4];
        float v[4];
#pragma unroll
        for (int j = 0; j < 4; ++j) {          // 3 independent coalesced loads x4
            const int e = tid + j * EQ;
            r[j] = row[e];
            c[j] = col[e];
            v[j] = vals[e];
        }
        int pos[4];
#pragma unroll
        for (int j = 0; j < 4; ++j)            // 4 atomics in flight
            pos[j] = atomicAdd(&deg[r[j]], 1);
#pragma unroll
        for (int j = 0; j < 4; ++j)
            if (pos[j] < CAP)
                bucket[(size_t)r[j] * CAP + pos[j]] =
                    make_int2(c[j], __float_as_int(v[j]));
    } else if (tid < EQ + 3 * HH * HH) {
        int f = tid - EQ;                      // linear index into W_tcn [o][i][k3]
        int kk = f % 3;
        if (kk < 2) {
            int o = f / (HH * 3);
            int i = (f / 3) % HH;
            Wt[(kk * HH + i) * HH + o] = W_tcn[f];
        }
    }
}

// ---------------------------------------------------------------------------
// k34 fused: gather-aggregate (fp16 rows) -> LDS tile -> head GEMM -> y.
// Phase 1: 16 waves x 2 nodes = 32 nodes/block; wave gathers a node's edges
//   (coalesced 512B metadata + shfl broadcast, 8 row-loads in flight, masked
//   beyond deg), ReLUs, writes float4 directly into pool[row][k].
// Phase 2: 1024 thr = 64 rows x 8 og x 2 kq; 4 k per ds_read_b128
//   (32 FMA/LDS-read); Wt via wave-uniform s_loads; stride-9 LDS reduction;
//   pool reused as hl[o*65+row]; epilogue reads W_out via wave-uniform
//   s_loads directly (no LDS staging).
// ---------------------------------------------------------------------------
__global__ __launch_bounds__(1024, 8) void k34_fused(
        const __half* __restrict__ hsmall, const int* __restrict__ deg,
        const int2* __restrict__ bucket, const float* __restrict__ Wt,
        const float* __restrict__ b_tcn, const float* __restrict__ W_out,
        const float* __restrict__ b_out, float* __restrict__ y) {
    __shared__ float pool[64 * RS];    // 33.8 KB: gathered tile, then hl
    __shared__ float red[512 * 9];     // 18.4 KB: kq=1 partials, stride-9
    const int t    = threadIdx.x;      // 0..1023
    const int lane = t & 63;
    const int w    = __builtin_amdgcn_readfirstlane(t >> 6);  // wave 0..15
    const int n0   = blockIdx.x * 32;

    // ---- phase 1: gather 2 nodes per wave, write tile directly ----
#pragma unroll
    for (int i = 0; i < 2; ++i) {
        const int nn = 2 * w + i;              // 0..31
        const int n  = n0 + nn;                // wave-uniform
        float4 acc = make_float4(0.f, 0.f, 0.f, 0.f);
        if (n < NN) {
            const int dn  = min(deg[n], CAP);
            const int dnp = (dn + 7) & ~7;
            const int2 meta = bucket[(size_t)n * CAP + lane];  // masked beyond dn
            for (int e0 = 0; e0 < dnp; e0 += 8) {
                int   c[8];
                float v[8];
#pragma unroll
                for (int j = 0; j < 8; ++j) {
                    int idx = e0 + j;
                    int   cc = __shfl(meta.x, idx);
                    float vv = __int_as_float(__shfl(meta.y, idx));
                    bool ok = idx < dn;
                    c[j] = ok ? cc : 0;
                    v[j] = ok ? vv : 0.f;
                }
                uint2 hv[8];
#pragma unroll
                for (int j = 0; j < 8; ++j)
                    hv[j] = *(const uint2*)((const char*)hsmall +
                                            ((size_t)c[j] * BLH + lane * 4) * 2);
#pragma unroll
                for (int j = 0; j < 8; ++j) {
                    float2 f0 = __half22float2(*(const __half2*)&hv[j].x);
                    float2 f1 = __half22float2(*(const __half2*)&hv[j].y);
                    acc.x = fmaf(v[j], f0.x, acc.x);
                    acc.y = fmaf(v[j], f0.y, acc.y);
                    acc.z = fmaf(v[j], f1.x, acc.z);
                    acc.w = fmaf(v[j], f1.y, acc.w);
                }
            }
        }
        // ReLU -> pool[row][k]; j0=4*lane; row=2nn+(j0>>7); k=j0&127
        const int j0  = 4 * lane;
        const int row = nn * 2 + (j0 >> 7);
        const int k   = j0 & 127;
        float4 r = make_float4(fmaxf(acc.x, 0.f), fmaxf(acc.y, 0.f),
                               fmaxf(acc.z, 0.f), fmaxf(acc.w, 0.f));
        *(float4*)&pool[row * RS + k] = r;     // aligned b128 write
    }
    __syncthreads();

    // ---- phase 2: head GEMM ----
    const int row = t & 63;
    const int og  = __builtin_amdgcn_readfirstlane((t >> 6) & 7);
    const int kq  = __builtin_amdgcn_readfirstlane(t >> 9);

    const float4* Wt4 = (const float4*)Wt;    // Wt[k*64+o] -> float4 idx k*16+o/4
    float acc[8];
#pragma unroll
    for (int j = 0; j < 8; ++j) acc[j] = 0.f;

    const int kbase = kq * 64;
#pragma unroll 4
    for (int kk = 0; kk < 16; ++kk) {
        const int k0 = kbase + kk * 4;
        float4 s4 = *(const float4*)&pool[row * RS + k0];   // 1 ds_read_b128 = 4 k
        float sv[4] = {s4.x, s4.y, s4.z, s4.w};
#pragma unroll
        for (int j = 0; j < 4; ++j) {
            const int k = k0 + j;
            float4 w0 = Wt4[k * 16 + og * 2 + 0];   // wave-uniform -> s_load
            float4 w1 = Wt4[k * 16 + og * 2 + 1];
            float v = sv[j];
            acc[0] = fmaf(v, w0.x, acc[0]); acc[1] = fmaf(v, w0.y, acc[1]);
            acc[2] = fmaf(v, w0.z, acc[2]); acc[3] = fmaf(v, w0.w, acc[3]);
            acc[4] = fmaf(v, w1.x, acc[4]); acc[5] = fmaf(v, w1.y, acc[5]);
            acc[6] = fmaf(v, w1.z, acc[6]); acc[7] = fmaf(v, w1.w, acc[7]);
        }
    }
    if (kq == 1) {
#pragma unroll
        for (int j = 0; j < 8; ++j) red[(t - 512) * 9 + j] = acc[j];
    }
    __syncthreads();   // all tile reads done; pool reusable as hl

    if (kq == 0) {
        const float4* bt4 = (const float4*)b_tcn;   // wave-uniform scalar loads
        float4 b0 = bt4[og * 2 + 0], b1 = bt4[og * 2 + 1];
        float bt[8] = {b0.x, b0.y, b0.z, b0.w, b1.x, b1.y, b1.z, b1.w};
#pragma unroll
        for (int j = 0; j < 8; ++j) {
            float s2 = acc[j] + red[t * 9 + j];
            pool[(og * 8 + j) * 65 + row] = fmaxf(s2 + bt[j], 0.f);  // hl[o][row]
        }
    }
    __syncthreads();

    // epilogue: 768 outputs = 64 rows (n,b encoded) x 12 p; p wave-uniform
    // -> W_out/b_out ride the scalar path directly (no LDS staging)
    if (t < 64 * PP) {
        int r2 = t & 63, p = t >> 6;           // p in 0..11
        int n = n0 + (r2 >> 1), b = r2 & 1;
        float yy = b_out[p];
#pragma unroll 8
        for (int o = 0; o < HH; ++o)
            yy = fmaf(pool[o * 65 + r2], W_out[o * PP + p], yy);
        if (n < NN) y[((size_t)(b * PP + p)) * NN + n] = yy;
    }
}

// ---------------------------------------------------------------------------
extern "C" void kernel_launch(void* const* d_in, const int* in_sizes, int n_in,
                              void* d_out, int out_size, void* d_ws, size_t ws_size,
                              hipStream_t stream) {
    const float* x     = (const float*)d_in[0];
    const int*   row   = (const int*)d_in[1];
    const int*   col   = (const int*)d_in[2];
    const float* vals  = (const float*)d_in[3];
    const float* W_in  = (const float*)d_in[4];
    const float* b_in  = (const float*)d_in[5];
    const float* W_tcn = (const float*)d_in[6];
    const float* b_tcn = (const float*)d_in[7];
    const float* W_out = (const float*)d_in[8];
    const float* b_out = (const float*)d_in[9];
    float* y = (float*)d_out;

    char* ws = (char*)d_ws;
    __half* hsmall = (__half*)(ws);                  //  5,120,000 B (fp16)
    int*    deg    = (int*)(ws + 5120000);           //     40,000 B
    int2*   bucket = (int2*)(ws + 5160000);          //  5,120,000 B
    float*  Wt     = (float*)(ws + 10280000);        //     32,768 B

    k1_input_proj<<<NN / 4, 256, 0, stream>>>(x, W_in, b_in, hsmall, deg);
    // 20000 edge-threads (4 edges each) + 12288 Wt-pack threads -> 127 blocks
    k2_build<<<(EQ + 3 * HH * HH + 255) / 256, 256, 0, stream>>>(
        row, col, vals, deg, bucket, W_tcn, Wt);
    // 32 nodes per block (16 waves x 2 nodes) -> 313 blocks
    k34_fused<<<(NN + 31) / 32, 1024, 0, stream>>>(hsmall, deg, bucket, Wt,
                                                   b_tcn, W_out, b_out, y);
}

// Round 17
// 102.794 us; speedup vs baseline: 1.0152x; 1.0152x over previous
//
#include <hip/hip_runtime.h>
#include <hip/hip_fp16.h>

// Problem constants: B=2, L=16, N=10000, FIN=8, H=64, P=12, E=80000, K=3
#define NN   10000
#define LL   16
#define FINC 8
#define HH   64
#define PP   12
#define EE   80000
#define BLH  256   // (b,lp,h) = 2*2*64 — only l=14,15 feed out[:,:,-1] (K=3, pad=1)
#define CAP  64    // per-row edge bucket capacity; E/N = 8, P(deg>64) ~ 0
#define RS   132   // fused-tile row stride (pad 128+4): 16B-aligned

// ---------------------------------------------------------------------------
// k1 v3h: 2500 blocks x 256 threads, 4 nodes per block (fully unrolled).
// W_in in registers; x via wave-uniform scalar loads; OUTPUT IN FP16
// (halves the L3-BW-bound gather traffic).  Blocks 0..39 zero deg.
// ---------------------------------------------------------------------------
__global__ __launch_bounds__(256) void k1_input_proj(
        const float* __restrict__ x, const float* __restrict__ W_in,
        const float* __restrict__ b_in, __half* __restrict__ hsmall,
        int* __restrict__ deg) {
    const int t  = threadIdx.x;
    const int bl = __builtin_amdgcn_readfirstlane(t >> 6);  // wave-uniform (b*2+lp)
    const int h  = t & 63;
    const int b  = bl >> 1, lp = bl & 1;

    if (blockIdx.x < 40) {                 // zero deg (10000 ints over 40 blocks)
        int di = blockIdx.x * 256 + t;
        if (di < NN) deg[di] = 0;
    }

    float w[FINC];
#pragma unroll
    for (int f = 0; f < FINC; ++f) w[f] = W_in[f * HH + h];   // coalesced, L2-hot
    const float bias = b_in[h];
    const float* xb = x + (size_t)(b * LL + 14 + lp) * NN * FINC;
    const int g = blockIdx.x * 4;

#pragma unroll
    for (int nn = 0; nn < 4; ++nn) {
        const int n = g + nn;
        float4 xa = *(const float4*)&xb[(size_t)n * 8];       // uniform -> s_load
        float4 xc = *(const float4*)&xb[(size_t)n * 8 + 4];
        float acc = bias;
        acc = fmaf(xa.x, w[0], acc); acc = fmaf(xa.y, w[1], acc);
        acc = fmaf(xa.z, w[2], acc); acc = fmaf(xa.w, w[3], acc);
        acc = fmaf(xc.x, w[4], acc); acc = fmaf(xc.y, w[5], acc);
        acc = fmaf(xc.z, w[6], acc); acc = fmaf(xc.w, w[7], acc);
        hsmall[(size_t)n * BLH + t] = __float2half_rn(fmaxf(acc, 0.f));
    }
}

// ---------------------------------------------------------------------------
// k2: bucketed CSR build + pack W_tcn taps {0,1} into Wt[k][o] (k = lp*64+i).
// ---------------------------------------------------------------------------
__global__ __launch_bounds__(256) void k2_build(
        const int* __restrict__ row, const int* __restrict__ col,
        const float* __restrict__ vals, int* __restrict__ deg,
        int2* __restrict__ bucket, const float* __restrict__ W_tcn,
        float* __restrict__ Wt) {
    int e = blockIdx.x * 256 + threadIdx.x;
    if (e < EE) {
        int r = row[e];
        int pos = atomicAdd(&deg[r], 1);
        if (pos < CAP)
            bucket[(size_t)r * CAP + pos] = make_int2(col[e], __float_as_int(vals[e]));
    } else if (e < EE + 3 * HH * HH) {
        int f = e - EE;                 // linear index into W_tcn [o][i][k3]
        int kk = f % 3;
        if (kk < 2) {
            int o = f / (HH * 3);
            int i = (f / 3) % HH;
            Wt[(kk * HH + i) * HH + o] = W_tcn[f];
        }
    }
}

// ---------------------------------------------------------------------------
// k34 fused: gather-aggregate (fp16 rows) -> LDS tile -> head GEMM -> y.
// Phase 1: 16 waves x 2 nodes = 32 nodes/block; wave gathers a node's edges
//   (coalesced 512B metadata + shfl broadcast, 8 row-loads in flight, masked
//   beyond deg), ReLUs, writes float4 directly into pool[row][k].
// Phase 2: 1024 thr = 64 rows x 8 og x 2 kq; 4 k per ds_read_b128
//   (32 FMA/LDS-read); Wt via wave-uniform s_loads; stride-9 LDS reduction;
//   pool reused as hl[o*65+row]; 768-output epilogue via LDS-staged Wo.
// ---------------------------------------------------------------------------
__global__ __launch_bounds__(1024, 8) void k34_fused(
        const __half* __restrict__ hsmall, const int* __restrict__ deg,
        const int2* __restrict__ bucket, const float* __restrict__ Wt,
        const float* __restrict__ b_tcn, const float* __restrict__ W_out,
        const float* __restrict__ b_out, float* __restrict__ y) {
    __shared__ float pool[64 * RS];    // 33.8 KB: gathered tile, then hl
    __shared__ float red[512 * 9];     // 18.4 KB: kq=1 partials, stride-9
    __shared__ float Wo[HH * PP];      // 3 KB
    const int t    = threadIdx.x;      // 0..1023
    const int lane = t & 63;
    const int w    = __builtin_amdgcn_readfirstlane(t >> 6);  // wave 0..15
    const int n0   = blockIdx.x * 32;

    for (int idx = t; idx < HH * PP; idx += 1024) Wo[idx] = W_out[idx];

    // ---- phase 1: gather 2 nodes per wave, write tile directly ----
#pragma unroll
    for (int i = 0; i < 2; ++i) {
        const int nn = 2 * w + i;              // 0..31
        const int n  = n0 + nn;                // wave-uniform
        float4 acc = make_float4(0.f, 0.f, 0.f, 0.f);
        if (n < NN) {
            const int dn  = min(deg[n], CAP);
            const int dnp = (dn + 7) & ~7;
            const int2 meta = bucket[(size_t)n * CAP + lane];  // masked beyond dn
            for (int e0 = 0; e0 < dnp; e0 += 8) {
                int   c[8];
                float v[8];
#pragma unroll
                for (int j = 0; j < 8; ++j) {
                    int idx = e0 + j;
                    int   cc = __shfl(meta.x, idx);
                    float vv = __int_as_float(__shfl(meta.y, idx));
                    bool ok = idx < dn;
                    c[j] = ok ? cc : 0;
                    v[j] = ok ? vv : 0.f;
                }
                uint2 hv[8];
#pragma unroll
                for (int j = 0; j < 8; ++j)
                    hv[j] = *(const uint2*)((const char*)hsmall +
                                            ((size_t)c[j] * BLH + lane * 4) * 2);
#pragma unroll
                for (int j = 0; j < 8; ++j) {
                    float2 f0 = __half22float2(*(const __half2*)&hv[j].x);
                    float2 f1 = __half22float2(*(const __half2*)&hv[j].y);
                    acc.x = fmaf(v[j], f0.x, acc.x);
                    acc.y = fmaf(v[j], f0.y, acc.y);
                    acc.z = fmaf(v[j], f1.x, acc.z);
                    acc.w = fmaf(v[j], f1.y, acc.w);
                }
            }
        }
        // ReLU -> pool[row][k]; j0=4*lane; row=2nn+(j0>>7); k=j0&127
        const int j0  = 4 * lane;
        const int row = nn * 2 + (j0 >> 7);
        const int k   = j0 & 127;
        float4 r = make_float4(fmaxf(acc.x, 0.f), fmaxf(acc.y, 0.f),
                               fmaxf(acc.z, 0.f), fmaxf(acc.w, 0.f));
        *(float4*)&pool[row * RS + k] = r;     // aligned b128 write
    }
    __syncthreads();

    // ---- phase 2: head GEMM ----
    const int row = t & 63;
    const int og  = __builtin_amdgcn_readfirstlane((t >> 6) & 7);
    const int kq  = __builtin_amdgcn_readfirstlane(t >> 9);

    const float4* Wt4 = (const float4*)Wt;    // Wt[k*64+o] -> float4 idx k*16+o/4
    float acc[8];
#pragma unroll
    for (int j = 0; j < 8; ++j) acc[j] = 0.f;

    const int kbase = kq * 64;
#pragma unroll 4
    for (int kk = 0; kk < 16; ++kk) {
        const int k0 = kbase + kk * 4;
        float4 s4 = *(const float4*)&pool[row * RS + k0];   // 1 ds_read_b128 = 4 k
        float sv[4] = {s4.x, s4.y, s4.z, s4.w};
#pragma unroll
        for (int j = 0; j < 4; ++j) {
            const int k = k0 + j;
            float4 w0 = Wt4[k * 16 + og * 2 + 0];   // wave-uniform -> s_load
            float4 w1 = Wt4[k * 16 + og * 2 + 1];
            float v = sv[j];
            acc[0] = fmaf(v, w0.x, acc[0]); acc[1] = fmaf(v, w0.y, acc[1]);
            acc[2] = fmaf(v, w0.z, acc[2]); acc[3] = fmaf(v, w0.w, acc[3]);
            acc[4] = fmaf(v, w1.x, acc[4]); acc[5] = fmaf(v, w1.y, acc[5]);
            acc[6] = fmaf(v, w1.z, acc[6]); acc[7] = fmaf(v, w1.w, acc[7]);
        }
    }
    if (kq == 1) {
#pragma unroll
        for (int j = 0; j < 8; ++j) red[(t - 512) * 9 + j] = acc[j];
    }
    __syncthreads();   // all tile reads done; pool reusable as hl

    if (kq == 0) {
        const float4* bt4 = (const float4*)b_tcn;   // wave-uniform scalar loads
        float4 b0 = bt4[og * 2 + 0], b1 = bt4[og * 2 + 1];
        float bt[8] = {b0.x, b0.y, b0.z, b0.w, b1.x, b1.y, b1.z, b1.w};
#pragma unroll
        for (int j = 0; j < 8; ++j) {
            float s2 = acc[j] + red[t * 9 + j];
            pool[(og * 8 + j) * 65 + row] = fmaxf(s2 + bt[j], 0.f);  // hl[o][row]
        }
    }
    __syncthreads();

    // epilogue: 768 outputs = 64 rows (n,b encoded) x 12 p
    if (t < 64 * PP) {
        int r2 = t & 63, p = t >> 6;           // p in 0..11
        int n = n0 + (r2 >> 1), b = r2 & 1;
        float yy = b_out[p];
#pragma unroll 8
        for (int o = 0; o < HH; ++o)
            yy = fmaf(pool[o * 65 + r2], Wo[o * PP + p], yy);
        if (n < NN) y[((size_t)(b * PP + p)) * NN + n] = yy;
    }
}

// ---------------------------------------------------------------------------
extern "C" void kernel_launch(void* const* d_in, const int* in_sizes, int n_in,
                              void* d_out, int out_size, void* d_ws, size_t ws_size,
                              hipStream_t stream) {
    const float* x     = (const float*)d_in[0];
    const int*   row   = (const int*)d_in[1];
    const int*   col   = (const int*)d_in[2];
    const float* vals  = (const float*)d_in[3];
    const float* W_in  = (const float*)d_in[4];
    const float* b_in  = (const float*)d_in[5];
    const float* W_tcn = (const float*)d_in[6];
    const float* b_tcn = (const float*)d_in[7];
    const float* W_out = (const float*)d_in[8];
    const float* b_out = (const float*)d_in[9];
    float* y = (float*)d_out;

    char* ws = (char*)d_ws;
    __half* hsmall = (__half*)(ws);                  //  5,120,000 B (fp16)
    int*    deg    = (int*)(ws + 5120000);           //     40,000 B
    int2*   bucket = (int2*)(ws + 5160000);          //  5,120,000 B
    float*  Wt     = (float*)(ws + 10280000);        //     32,768 B

    k1_input_proj<<<NN / 4, 256, 0, stream>>>(x, W_in, b_in, hsmall, deg);
    k2_build<<<(EE + 3 * HH * HH + 255) / 256, 256, 0, stream>>>(
        row, col, vals, deg, bucket, W_tcn, Wt);
    // 32 nodes per block (16 waves x 2 nodes) -> 313 blocks
    k34_fused<<<(NN + 31) / 32, 1024, 0, stream>>>(hsmall, deg, bucket, Wt,
                                                   b_tcn, W_out, b_out, y);
}